// Round 1
// baseline (1147.885 us; speedup 1.0000x reference)
//
#include <hip/hip_runtime.h>

#define NN 100000
#define NE 1600000
#define IN_DIM 32
#define HID_DIM 16
#define OUT_DIM 8

// ---------------- degree ----------------
__global__ void k_deg(const int* __restrict__ dst, float* __restrict__ deg) {
    int e = blockIdx.x * blockDim.x + threadIdx.x;
    if (e < NE) atomicAdd(&deg[dst[e]], 1.0f);
}

// ---------------- scatter-sum of x[src] (32 dims), 8 threads/edge, float4 each ----------------
__global__ void k_scatter32(const int* __restrict__ src, const int* __restrict__ dst,
                            const float* __restrict__ x, float* __restrict__ sum) {
    int tid = blockIdx.x * blockDim.x + threadIdx.x;
    int e = tid >> 3;          // edge index
    int c = tid & 7;           // float4 chunk within 32 dims
    if (e < NE) {
        int s = src[e], d = dst[e];
        float4 v = ((const float4*)x)[s * 8 + c];
        float* o = sum + d * 32 + c * 4;
        atomicAdd(o + 0, v.x);
        atomicAdd(o + 1, v.y);
        atomicAdd(o + 2, v.z);
        atomicAdd(o + 3, v.w);
    }
}

// ---------------- scatter-sum of h[src] (16 dims), 4 threads/edge ----------------
__global__ void k_scatter16(const int* __restrict__ src, const int* __restrict__ dst,
                            const float* __restrict__ h, float* __restrict__ sum) {
    int tid = blockIdx.x * blockDim.x + threadIdx.x;
    int e = tid >> 2;
    int c = tid & 3;
    if (e < NE) {
        int s = src[e], d = dst[e];
        float4 v = ((const float4*)h)[s * 4 + c];
        float* o = sum + d * 16 + c * 4;
        atomicAdd(o + 0, v.x);
        atomicAdd(o + 1, v.y);
        atomicAdd(o + 2, v.z);
        atomicAdd(o + 3, v.w);
    }
}

// ---------------- layer 1: h = relu(Wl1*mean + bl1 + Wr1*x) ----------------
__global__ void k_layer1(const float* __restrict__ x, const float* __restrict__ sum1,
                         const float* __restrict__ deg,
                         const float* __restrict__ Wl1, const float* __restrict__ bl1,
                         const float* __restrict__ Wr1, float* __restrict__ h) {
    __shared__ float sWl[HID_DIM * IN_DIM];
    __shared__ float sWr[HID_DIM * IN_DIM];
    __shared__ float sb[HID_DIM];
    for (int i = threadIdx.x; i < HID_DIM * IN_DIM; i += blockDim.x) {
        sWl[i] = Wl1[i];
        sWr[i] = Wr1[i];
    }
    if (threadIdx.x < HID_DIM) sb[threadIdx.x] = bl1[threadIdx.x];
    __syncthreads();

    int n = blockIdx.x * blockDim.x + threadIdx.x;
    if (n >= NN) return;

    float inv = 1.0f / fmaxf(deg[n], 1.0f);
    float m[IN_DIM], xv[IN_DIM];
    const float4* s4 = (const float4*)(sum1 + n * IN_DIM);
    const float4* x4 = (const float4*)(x + n * IN_DIM);
#pragma unroll
    for (int c = 0; c < 8; c++) {
        float4 a = s4[c];
        float4 b = x4[c];
        m[c * 4 + 0] = a.x * inv; m[c * 4 + 1] = a.y * inv;
        m[c * 4 + 2] = a.z * inv; m[c * 4 + 3] = a.w * inv;
        xv[c * 4 + 0] = b.x; xv[c * 4 + 1] = b.y;
        xv[c * 4 + 2] = b.z; xv[c * 4 + 3] = b.w;
    }
#pragma unroll
    for (int o = 0; o < HID_DIM; o++) {
        float acc = sb[o];
#pragma unroll
        for (int i = 0; i < IN_DIM; i++)
            acc += sWl[o * IN_DIM + i] * m[i] + sWr[o * IN_DIM + i] * xv[i];
        h[n * HID_DIM + o] = fmaxf(acc, 0.0f);
    }
}

// ---------------- layer 2 + fc head: out = Wfc*(Wl2*mean2 + bl2 + Wr2*h) + bfc ----------------
__global__ void k_layer2(const float* __restrict__ h, const float* __restrict__ sum2,
                         const float* __restrict__ deg,
                         const float* __restrict__ Wl2, const float* __restrict__ bl2,
                         const float* __restrict__ Wr2,
                         const float* __restrict__ Wfc, const float* __restrict__ bfc,
                         float* __restrict__ out) {
    __shared__ float sWl[OUT_DIM * HID_DIM];
    __shared__ float sWr[OUT_DIM * HID_DIM];
    __shared__ float sb[OUT_DIM];
    __shared__ float sWf[OUT_DIM];
    __shared__ float sbf;
    for (int i = threadIdx.x; i < OUT_DIM * HID_DIM; i += blockDim.x) {
        sWl[i] = Wl2[i];
        sWr[i] = Wr2[i];
    }
    if (threadIdx.x < OUT_DIM) {
        sb[threadIdx.x] = bl2[threadIdx.x];
        sWf[threadIdx.x] = Wfc[threadIdx.x];
    }
    if (threadIdx.x == 0) sbf = bfc[0];
    __syncthreads();

    int n = blockIdx.x * blockDim.x + threadIdx.x;
    if (n >= NN) return;

    float inv = 1.0f / fmaxf(deg[n], 1.0f);
    float m[HID_DIM], hv[HID_DIM];
    const float4* s4 = (const float4*)(sum2 + n * HID_DIM);
    const float4* h4 = (const float4*)(h + n * HID_DIM);
#pragma unroll
    for (int c = 0; c < 4; c++) {
        float4 a = s4[c];
        float4 b = h4[c];
        m[c * 4 + 0] = a.x * inv; m[c * 4 + 1] = a.y * inv;
        m[c * 4 + 2] = a.z * inv; m[c * 4 + 3] = a.w * inv;
        hv[c * 4 + 0] = b.x; hv[c * 4 + 1] = b.y;
        hv[c * 4 + 2] = b.z; hv[c * 4 + 3] = b.w;
    }
    float res = sbf;
#pragma unroll
    for (int o = 0; o < OUT_DIM; o++) {
        float acc = sb[o];
#pragma unroll
        for (int i = 0; i < HID_DIM; i++)
            acc += sWl[o * HID_DIM + i] * m[i] + sWr[o * HID_DIM + i] * hv[i];
        res += sWf[o] * acc;
    }
    out[n] = res;
}

extern "C" void kernel_launch(void* const* d_in, const int* in_sizes, int n_in,
                              void* d_out, int out_size, void* d_ws, size_t ws_size,
                              hipStream_t stream) {
    const float* x   = (const float*)d_in[0];
    const int*   ei  = (const int*)d_in[1];
    const float* Wl1 = (const float*)d_in[2];
    const float* bl1 = (const float*)d_in[3];
    const float* Wr1 = (const float*)d_in[4];
    const float* Wl2 = (const float*)d_in[5];
    const float* bl2 = (const float*)d_in[6];
    const float* Wr2 = (const float*)d_in[7];
    const float* Wfc = (const float*)d_in[8];
    const float* bfc = (const float*)d_in[9];
    float* out = (float*)d_out;

    const int* src = ei;
    const int* dst = ei + NE;

    // workspace layout: deg[NN] | sum1[NN*32] | sum2[NN*16] | h[NN*16]
    float* deg  = (float*)d_ws;
    float* sum1 = deg + NN;
    float* sum2 = sum1 + NN * IN_DIM;
    float* h    = sum2 + NN * HID_DIM;

    // zero deg + sum1 + sum2 (contiguous region)
    size_t zero_bytes = (size_t)(1 + IN_DIM + HID_DIM) * NN * sizeof(float);
    hipMemsetAsync(d_ws, 0, zero_bytes, stream);

    // degree
    k_deg<<<(NE + 255) / 256, 256, 0, stream>>>(dst, deg);

    // scatter layer-1 input
    {
        long long threads = (long long)NE * 8;
        k_scatter32<<<(threads + 255) / 256, 256, 0, stream>>>(src, dst, x, sum1);
    }

    // layer 1
    k_layer1<<<(NN + 255) / 256, 256, 0, stream>>>(x, sum1, deg, Wl1, bl1, Wr1, h);

    // scatter layer-2 input
    {
        long long threads = (long long)NE * 4;
        k_scatter16<<<(threads + 255) / 256, 256, 0, stream>>>(src, dst, h, sum2);
    }

    // layer 2 + head
    k_layer2<<<(NN + 255) / 256, 256, 0, stream>>>(h, sum2, deg, Wl2, bl2, Wr2, Wfc, bfc, out);
}

// Round 2
// 432.189 us; speedup vs baseline: 2.6560x; 2.6560x over previous
//
#include <hip/hip_runtime.h>

#define NN 100000
#define NE 1600000
#define IN_DIM 32
#define HID_DIM 16
#define OUT_DIM 8

#define SCAN_CHUNK 256
#define NB_SCAN ((NN + SCAN_CHUNK - 1) / SCAN_CHUNK)   // 391

// ---------------- count degrees (int atomics) ----------------
__global__ void k_count(const int* __restrict__ dst, int* __restrict__ cnt) {
    int e = blockIdx.x * blockDim.x + threadIdx.x;
    if (e < NE) atomicAdd(&cnt[dst[e]], 1);
}

// ---------------- per-block reduction of counts ----------------
__global__ void k_bsum(const int* __restrict__ cnt, int* __restrict__ bsum) {
    __shared__ int s[SCAN_CHUNK];
    int t = threadIdx.x;
    int idx = blockIdx.x * SCAN_CHUNK + t;
    s[t] = (idx < NN) ? cnt[idx] : 0;
    __syncthreads();
    for (int off = SCAN_CHUNK / 2; off > 0; off >>= 1) {
        if (t < off) s[t] += s[t + off];
        __syncthreads();
    }
    if (t == 0) bsum[blockIdx.x] = s[0];
}

// ---------------- scan block sums (single block, 512 threads) ----------------
__global__ void k_scan_bsum(int* __restrict__ bsum) {
    __shared__ int s[512];
    int t = threadIdx.x;
    int v = (t < NB_SCAN) ? bsum[t] : 0;
    s[t] = v;
    __syncthreads();
    for (int off = 1; off < 512; off <<= 1) {
        int tv = (t >= off) ? s[t - off] : 0;
        __syncthreads();
        s[t] += tv;
        __syncthreads();
    }
    if (t < NB_SCAN) bsum[t] = s[t] - v;   // exclusive
}

// ---------------- write row starts into fill[] ----------------
__global__ void k_starts(const int* __restrict__ cnt, const int* __restrict__ bsum,
                         int* __restrict__ fill) {
    __shared__ int s[SCAN_CHUNK];
    int t = threadIdx.x;
    int idx = blockIdx.x * SCAN_CHUNK + t;
    int v = (idx < NN) ? cnt[idx] : 0;
    s[t] = v;
    __syncthreads();
    for (int off = 1; off < SCAN_CHUNK; off <<= 1) {
        int tv = (t >= off) ? s[t - off] : 0;
        __syncthreads();
        s[t] += tv;
        __syncthreads();
    }
    if (idx < NN) fill[idx] = bsum[blockIdx.x] + s[t] - v;  // exclusive start
}

// ---------------- fill CSR: srcs ordered by dst ----------------
__global__ void k_fill(const int* __restrict__ src, const int* __restrict__ dst,
                       int* __restrict__ fill, int* __restrict__ srcs) {
    int e = blockIdx.x * blockDim.x + threadIdx.x;
    if (e < NE) {
        int pos = atomicAdd(&fill[dst[e]], 1);
        srcs[pos] = src[e];
    }
}
// after k_fill: fill[n] == row end; start = fill[n] - cnt[n]

// ---------------- gather-mean of x (32 dims), 32 threads/node ----------------
__global__ void k_gather32(const int* __restrict__ srcs, const int* __restrict__ cnt,
                           const int* __restrict__ fillEnd,
                           const float* __restrict__ x, float* __restrict__ mean) {
    int tid = blockIdx.x * blockDim.x + threadIdx.x;
    int n = tid >> 5;
    int c = tid & 31;
    if (n >= NN) return;
    int deg = cnt[n];
    int start = fillEnd[n] - deg;
    float acc = 0.0f;
    for (int i = 0; i < deg; i++) {
        int s = srcs[start + i];          // broadcast within the 32-lane group
        acc += x[s * IN_DIM + c];         // 32 lanes -> 128B coalesced row read
    }
    float inv = 1.0f / fmaxf((float)deg, 1.0f);
    mean[n * IN_DIM + c] = acc * inv;
}

// ---------------- gather-mean of h (16 dims), 16 threads/node ----------------
__global__ void k_gather16(const int* __restrict__ srcs, const int* __restrict__ cnt,
                           const int* __restrict__ fillEnd,
                           const float* __restrict__ h, float* __restrict__ mean) {
    int tid = blockIdx.x * blockDim.x + threadIdx.x;
    int n = tid >> 4;
    int c = tid & 15;
    if (n >= NN) return;
    int deg = cnt[n];
    int start = fillEnd[n] - deg;
    float acc = 0.0f;
    for (int i = 0; i < deg; i++) {
        int s = srcs[start + i];
        acc += h[s * HID_DIM + c];        // 16 lanes -> 64B coalesced row read
    }
    float inv = 1.0f / fmaxf((float)deg, 1.0f);
    mean[n * HID_DIM + c] = acc * inv;
}

// ---------------- layer 1: h = relu(Wl1*mean + bl1 + Wr1*x) ----------------
__global__ void k_layer1(const float* __restrict__ x, const float* __restrict__ mean1,
                         const float* __restrict__ Wl1, const float* __restrict__ bl1,
                         const float* __restrict__ Wr1, float* __restrict__ h) {
    __shared__ float sWl[HID_DIM * IN_DIM];
    __shared__ float sWr[HID_DIM * IN_DIM];
    __shared__ float sb[HID_DIM];
    for (int i = threadIdx.x; i < HID_DIM * IN_DIM; i += blockDim.x) {
        sWl[i] = Wl1[i];
        sWr[i] = Wr1[i];
    }
    if (threadIdx.x < HID_DIM) sb[threadIdx.x] = bl1[threadIdx.x];
    __syncthreads();

    int n = blockIdx.x * blockDim.x + threadIdx.x;
    if (n >= NN) return;

    float m[IN_DIM], xv[IN_DIM];
    const float4* s4 = (const float4*)(mean1 + n * IN_DIM);
    const float4* x4 = (const float4*)(x + n * IN_DIM);
#pragma unroll
    for (int c = 0; c < 8; c++) {
        float4 a = s4[c];
        float4 b = x4[c];
        m[c * 4 + 0] = a.x; m[c * 4 + 1] = a.y; m[c * 4 + 2] = a.z; m[c * 4 + 3] = a.w;
        xv[c * 4 + 0] = b.x; xv[c * 4 + 1] = b.y; xv[c * 4 + 2] = b.z; xv[c * 4 + 3] = b.w;
    }
#pragma unroll
    for (int o = 0; o < HID_DIM; o++) {
        float acc = sb[o];
#pragma unroll
        for (int i = 0; i < IN_DIM; i++)
            acc += sWl[o * IN_DIM + i] * m[i] + sWr[o * IN_DIM + i] * xv[i];
        h[n * HID_DIM + o] = fmaxf(acc, 0.0f);
    }
}

// ---------------- layer 2 + fc head ----------------
__global__ void k_layer2(const float* __restrict__ h, const float* __restrict__ mean2,
                         const float* __restrict__ Wl2, const float* __restrict__ bl2,
                         const float* __restrict__ Wr2,
                         const float* __restrict__ Wfc, const float* __restrict__ bfc,
                         float* __restrict__ out) {
    __shared__ float sWl[OUT_DIM * HID_DIM];
    __shared__ float sWr[OUT_DIM * HID_DIM];
    __shared__ float sb[OUT_DIM];
    __shared__ float sWf[OUT_DIM];
    __shared__ float sbf;
    for (int i = threadIdx.x; i < OUT_DIM * HID_DIM; i += blockDim.x) {
        sWl[i] = Wl2[i];
        sWr[i] = Wr2[i];
    }
    if (threadIdx.x < OUT_DIM) {
        sb[threadIdx.x] = bl2[threadIdx.x];
        sWf[threadIdx.x] = Wfc[threadIdx.x];
    }
    if (threadIdx.x == 0) sbf = bfc[0];
    __syncthreads();

    int n = blockIdx.x * blockDim.x + threadIdx.x;
    if (n >= NN) return;

    float m[HID_DIM], hv[HID_DIM];
    const float4* s4 = (const float4*)(mean2 + n * HID_DIM);
    const float4* h4 = (const float4*)(h + n * HID_DIM);
#pragma unroll
    for (int c = 0; c < 4; c++) {
        float4 a = s4[c];
        float4 b = h4[c];
        m[c * 4 + 0] = a.x; m[c * 4 + 1] = a.y; m[c * 4 + 2] = a.z; m[c * 4 + 3] = a.w;
        hv[c * 4 + 0] = b.x; hv[c * 4 + 1] = b.y; hv[c * 4 + 2] = b.z; hv[c * 4 + 3] = b.w;
    }
    float res = sbf;
#pragma unroll
    for (int o = 0; o < OUT_DIM; o++) {
        float acc = sb[o];
#pragma unroll
        for (int i = 0; i < HID_DIM; i++)
            acc += sWl[o * HID_DIM + i] * m[i] + sWr[o * HID_DIM + i] * hv[i];
        res += sWf[o] * acc;
    }
    out[n] = res;
}

extern "C" void kernel_launch(void* const* d_in, const int* in_sizes, int n_in,
                              void* d_out, int out_size, void* d_ws, size_t ws_size,
                              hipStream_t stream) {
    const float* x   = (const float*)d_in[0];
    const int*   ei  = (const int*)d_in[1];
    const float* Wl1 = (const float*)d_in[2];
    const float* bl1 = (const float*)d_in[3];
    const float* Wr1 = (const float*)d_in[4];
    const float* Wl2 = (const float*)d_in[5];
    const float* bl2 = (const float*)d_in[6];
    const float* Wr2 = (const float*)d_in[7];
    const float* Wfc = (const float*)d_in[8];
    const float* bfc = (const float*)d_in[9];
    float* out = (float*)d_out;

    const int* src = ei;
    const int* dst = ei + NE;

    // ws layout: cnt[NN] | fill[NN] | bsum[512] | srcs[NE] | mean1[NN*32] | h[NN*16]
    // mean2 aliases mean1 (mean1 is dead after k_layer1)
    int*   cnt   = (int*)d_ws;
    int*   fill  = cnt + NN;
    int*   bsum  = fill + NN;
    int*   srcs  = bsum + 512;
    float* mean1 = (float*)(srcs + NE);
    float* h     = mean1 + (size_t)NN * IN_DIM;
    float* mean2 = mean1;   // alias: safe, mean1 consumed before mean2 written

    // zero cnt only
    hipMemsetAsync(cnt, 0, NN * sizeof(int), stream);

    k_count<<<(NE + 255) / 256, 256, 0, stream>>>(dst, cnt);
    k_bsum<<<NB_SCAN, SCAN_CHUNK, 0, stream>>>(cnt, bsum);
    k_scan_bsum<<<1, 512, 0, stream>>>(bsum);
    k_starts<<<NB_SCAN, SCAN_CHUNK, 0, stream>>>(cnt, bsum, fill);
    k_fill<<<(NE + 255) / 256, 256, 0, stream>>>(src, dst, fill, srcs);
    // fill[n] is now row END; start = fill[n] - cnt[n]

    k_gather32<<<((NN * 32) + 255) / 256, 256, 0, stream>>>(srcs, cnt, fill, x, mean1);
    k_layer1<<<(NN + 255) / 256, 256, 0, stream>>>(x, mean1, Wl1, bl1, Wr1, h);
    k_gather16<<<((NN * 16) + 255) / 256, 256, 0, stream>>>(srcs, cnt, fill, h, mean2);
    k_layer2<<<(NN + 255) / 256, 256, 0, stream>>>(h, mean2, Wl2, bl2, Wr2, Wfc, bfc, out);
}

// Round 3
// 218.061 us; speedup vs baseline: 5.2641x; 1.9820x over previous
//
#include <hip/hip_runtime.h>

#define NN 100000
#define NE 1600000
#define IN_DIM 32
#define HID_DIM 16
#define OUT_DIM 8

#define NPB 256                      // nodes per bucket (power of 2)
#define NB  ((NN + NPB - 1) / NPB)   // 391 buckets
#define CAP 5632                     // bucket capacity (mean 4096, ~24 sigma)
#define EPB 4096                     // edges per block in k_bucket
#define NBLK_BUCKET ((NE + EPB - 1) / EPB)   // 391

// ---------------- pass 1: bucket edges by dst>>8, packed (src<<8 | dst&255) ----------------
__global__ void k_bucket(const int* __restrict__ src, const int* __restrict__ dst,
                         int* __restrict__ bucketfill, unsigned int* __restrict__ bucket) {
    __shared__ int lcnt[NB];
    __shared__ int lbase[NB];
    __shared__ int lfill[NB];
    int t = threadIdx.x;
    int e0 = blockIdx.x * EPB;
    int e1 = min(e0 + EPB, NE);
    for (int i = t; i < NB; i += 256) lcnt[i] = 0;
    __syncthreads();
    for (int e = e0 + t; e < e1; e += 256) atomicAdd(&lcnt[dst[e] >> 8], 1);
    __syncthreads();
    for (int i = t; i < NB; i += 256) {
        lbase[i] = (lcnt[i] > 0) ? atomicAdd(&bucketfill[i], lcnt[i]) : 0;
        lfill[i] = 0;
    }
    __syncthreads();
    for (int e = e0 + t; e < e1; e += 256) {
        int d = dst[e], s = src[e];
        int b = d >> 8;
        int p = atomicAdd(&lfill[b], 1);
        bucket[(size_t)b * CAP + lbase[b] + p] = (unsigned)(d & (NPB - 1)) | ((unsigned)s << 8);
    }
}

// ---------------- scan bucket counts -> bucket bases (1 block) ----------------
__global__ void k_scan_nb(const int* __restrict__ bucketfill, int* __restrict__ bucketbase) {
    __shared__ int sdat[512];
    int t = threadIdx.x;
    int v = (t < NB) ? bucketfill[t] : 0;
    sdat[t] = v;
    __syncthreads();
    for (int off = 1; off < 512; off <<= 1) {
        int tv = (t >= off) ? sdat[t - off] : 0;
        __syncthreads();
        sdat[t] += tv;
        __syncthreads();
    }
    if (t < NB) bucketbase[t] = sdat[t] - v;   // exclusive
}

// ---------------- pass 2: per-bucket LDS counting sort -> deg, rowstart, srcs ----------------
__global__ void k_sort(const int* __restrict__ bucketfill, const int* __restrict__ bucketbase,
                       const unsigned int* __restrict__ bucket,
                       int* __restrict__ deg, int* __restrict__ rowstart,
                       int* __restrict__ srcs) {
    __shared__ int lcnt[NPB];
    __shared__ int lscan[NPB];
    __shared__ int lfill[NPB];
    int b = blockIdx.x;
    int t = threadIdx.x;
    int cntb = bucketfill[b];
    int base = bucketbase[b];
    const unsigned int* bk = bucket + (size_t)b * CAP;
    lcnt[t] = 0;
    __syncthreads();
    for (int i = t; i < cntb; i += NPB) atomicAdd(&lcnt[bk[i] & (NPB - 1)], 1);
    __syncthreads();
    lscan[t] = lcnt[t];
    __syncthreads();
    for (int off = 1; off < NPB; off <<= 1) {
        int tv = (t >= off) ? lscan[t - off] : 0;
        __syncthreads();
        lscan[t] += tv;
        __syncthreads();
    }
    int excl = lscan[t] - lcnt[t];
    int node = b * NPB + t;
    if (node < NN) { deg[node] = lcnt[t]; rowstart[node] = base + excl; }
    lfill[t] = excl;
    __syncthreads();
    for (int i = t; i < cntb; i += NPB) {
        unsigned v = bk[i];
        int d = v & (NPB - 1);
        int p = atomicAdd(&lfill[d], 1);
        srcs[base + p] = (int)(v >> 8);
    }
}

// ---------------- gather-mean of x (32 dims), 8 lanes/node, float4 ----------------
__global__ void k_gather32(const int* __restrict__ srcs, const int* __restrict__ deg,
                           const int* __restrict__ rowstart,
                           const float* __restrict__ x, float* __restrict__ mean) {
    int tid = blockIdx.x * blockDim.x + threadIdx.x;
    int n = tid >> 3;
    int c = tid & 7;
    if (n >= NN) return;
    int dg = deg[n];
    int start = rowstart[n];
    float4 acc = {0.f, 0.f, 0.f, 0.f};
    for (int i = 0; i < dg; i++) {
        int s = srcs[start + i];
        float4 v = ((const float4*)x)[s * 8 + c];
        acc.x += v.x; acc.y += v.y; acc.z += v.z; acc.w += v.w;
    }
    float inv = 1.0f / fmaxf((float)dg, 1.0f);
    acc.x *= inv; acc.y *= inv; acc.z *= inv; acc.w *= inv;
    ((float4*)mean)[n * 8 + c] = acc;
}

// ---------------- gather-mean of h (16 dims), 4 lanes/node, float4 ----------------
__global__ void k_gather16(const int* __restrict__ srcs, const int* __restrict__ deg,
                           const int* __restrict__ rowstart,
                           const float* __restrict__ h, float* __restrict__ mean) {
    int tid = blockIdx.x * blockDim.x + threadIdx.x;
    int n = tid >> 2;
    int c = tid & 3;
    if (n >= NN) return;
    int dg = deg[n];
    int start = rowstart[n];
    float4 acc = {0.f, 0.f, 0.f, 0.f};
    for (int i = 0; i < dg; i++) {
        int s = srcs[start + i];
        float4 v = ((const float4*)h)[s * 4 + c];
        acc.x += v.x; acc.y += v.y; acc.z += v.z; acc.w += v.w;
    }
    float inv = 1.0f / fmaxf((float)dg, 1.0f);
    acc.x *= inv; acc.y *= inv; acc.z *= inv; acc.w *= inv;
    ((float4*)mean)[n * 4 + c] = acc;
}

// ---------------- layer 1: h = relu(Wl1*mean + bl1 + Wr1*x) ----------------
__global__ void k_layer1(const float* __restrict__ x, const float* __restrict__ mean1,
                         const float* __restrict__ Wl1, const float* __restrict__ bl1,
                         const float* __restrict__ Wr1, float* __restrict__ h) {
    __shared__ float sWl[HID_DIM * IN_DIM];
    __shared__ float sWr[HID_DIM * IN_DIM];
    __shared__ float sb[HID_DIM];
    for (int i = threadIdx.x; i < HID_DIM * IN_DIM; i += blockDim.x) {
        sWl[i] = Wl1[i];
        sWr[i] = Wr1[i];
    }
    if (threadIdx.x < HID_DIM) sb[threadIdx.x] = bl1[threadIdx.x];
    __syncthreads();

    int n = blockIdx.x * blockDim.x + threadIdx.x;
    if (n >= NN) return;

    float m[IN_DIM], xv[IN_DIM];
    const float4* s4 = (const float4*)(mean1 + n * IN_DIM);
    const float4* x4 = (const float4*)(x + n * IN_DIM);
#pragma unroll
    for (int c = 0; c < 8; c++) {
        float4 a = s4[c];
        float4 b = x4[c];
        m[c * 4 + 0] = a.x; m[c * 4 + 1] = a.y; m[c * 4 + 2] = a.z; m[c * 4 + 3] = a.w;
        xv[c * 4 + 0] = b.x; xv[c * 4 + 1] = b.y; xv[c * 4 + 2] = b.z; xv[c * 4 + 3] = b.w;
    }
#pragma unroll
    for (int o = 0; o < HID_DIM; o++) {
        float acc = sb[o];
#pragma unroll
        for (int i = 0; i < IN_DIM; i++)
            acc += sWl[o * IN_DIM + i] * m[i] + sWr[o * IN_DIM + i] * xv[i];
        h[n * HID_DIM + o] = fmaxf(acc, 0.0f);
    }
}

// ---------------- layer 2 + fc head ----------------
__global__ void k_layer2(const float* __restrict__ h, const float* __restrict__ mean2,
                         const float* __restrict__ Wl2, const float* __restrict__ bl2,
                         const float* __restrict__ Wr2,
                         const float* __restrict__ Wfc, const float* __restrict__ bfc,
                         float* __restrict__ out) {
    __shared__ float sWl[OUT_DIM * HID_DIM];
    __shared__ float sWr[OUT_DIM * HID_DIM];
    __shared__ float sb[OUT_DIM];
    __shared__ float sWf[OUT_DIM];
    __shared__ float sbf;
    for (int i = threadIdx.x; i < OUT_DIM * HID_DIM; i += blockDim.x) {
        sWl[i] = Wl2[i];
        sWr[i] = Wr2[i];
    }
    if (threadIdx.x < OUT_DIM) {
        sb[threadIdx.x] = bl2[threadIdx.x];
        sWf[threadIdx.x] = Wfc[threadIdx.x];
    }
    if (threadIdx.x == 0) sbf = bfc[0];
    __syncthreads();

    int n = blockIdx.x * blockDim.x + threadIdx.x;
    if (n >= NN) return;

    float m[HID_DIM], hv[HID_DIM];
    const float4* s4 = (const float4*)(mean2 + n * HID_DIM);
    const float4* h4 = (const float4*)(h + n * HID_DIM);
#pragma unroll
    for (int c = 0; c < 4; c++) {
        float4 a = s4[c];
        float4 b = h4[c];
        m[c * 4 + 0] = a.x; m[c * 4 + 1] = a.y; m[c * 4 + 2] = a.z; m[c * 4 + 3] = a.w;
        hv[c * 4 + 0] = b.x; hv[c * 4 + 1] = b.y; hv[c * 4 + 2] = b.z; hv[c * 4 + 3] = b.w;
    }
    float res = sbf;
#pragma unroll
    for (int o = 0; o < OUT_DIM; o++) {
        float acc = sb[o];
#pragma unroll
        for (int i = 0; i < HID_DIM; i++)
            acc += sWl[o * HID_DIM + i] * m[i] + sWr[o * HID_DIM + i] * hv[i];
        res += sWf[o] * acc;
    }
    out[n] = res;
}

extern "C" void kernel_launch(void* const* d_in, const int* in_sizes, int n_in,
                              void* d_out, int out_size, void* d_ws, size_t ws_size,
                              hipStream_t stream) {
    const float* x   = (const float*)d_in[0];
    const int*   ei  = (const int*)d_in[1];
    const float* Wl1 = (const float*)d_in[2];
    const float* bl1 = (const float*)d_in[3];
    const float* Wr1 = (const float*)d_in[4];
    const float* Wl2 = (const float*)d_in[5];
    const float* bl2 = (const float*)d_in[6];
    const float* Wr2 = (const float*)d_in[7];
    const float* Wfc = (const float*)d_in[8];
    const float* bfc = (const float*)d_in[9];
    float* out = (float*)d_out;

    const int* src = ei;
    const int* dst = ei + NE;

    // ws layout: bucketfill[NB] | bucketbase[NB] | deg[NN] | rowstart[NN] | srcs[NE] |
    //            union{ bucket[NB*CAP] (8.8MB) , mean1[NN*32] (12.8MB) } | h[NN*16]
    // bucket dead after k_sort; mean1 written by k_gather32 after that -> safe alias.
    int* bucketfill = (int*)d_ws;
    int* bucketbase = bucketfill + NB;
    int* deg        = bucketbase + NB;
    int* rowstart   = deg + NN;
    int* srcs       = rowstart + NN;
    unsigned int* bucket = (unsigned int*)(srcs + NE);
    float* mean1 = (float*)bucket;
    float* h     = mean1 + (size_t)NN * IN_DIM;
    float* mean2 = mean1;   // alias: mean1 consumed by k_layer1 before k_gather16 writes mean2

    hipMemsetAsync(bucketfill, 0, NB * sizeof(int), stream);

    k_bucket<<<NBLK_BUCKET, 256, 0, stream>>>(src, dst, bucketfill, bucket);
    k_scan_nb<<<1, 512, 0, stream>>>(bucketfill, bucketbase);
    k_sort<<<NB, NPB, 0, stream>>>(bucketfill, bucketbase, bucket, deg, rowstart, srcs);

    k_gather32<<<((size_t)NN * 8 + 255) / 256, 256, 0, stream>>>(srcs, deg, rowstart, x, mean1);
    k_layer1<<<(NN + 255) / 256, 256, 0, stream>>>(x, mean1, Wl1, bl1, Wr1, h);
    k_gather16<<<((size_t)NN * 4 + 255) / 256, 256, 0, stream>>>(srcs, deg, rowstart, h, mean2);
    k_layer2<<<(NN + 255) / 256, 256, 0, stream>>>(h, mean2, Wl2, bl2, Wr2, Wfc, bfc, out);
}

// Round 4
// 188.680 us; speedup vs baseline: 6.0838x; 1.1557x over previous
//
#include <hip/hip_runtime.h>

#define NN 100000
#define NE 1600000
#define IN_DIM 32
#define HID_DIM 16
#define OUT_DIM 8

#define NPB 256                      // nodes per bucket (power of 2)
#define NB  ((NN + NPB - 1) / NPB)   // 391 buckets
#define CAP 5632                     // bucket capacity (mean 4096, ~24 sigma)
#define EPB 4096                     // edges per block in k_bucket
#define NBLK_BUCKET ((NE + EPB - 1) / EPB)   // 391

// ---------------- pass 1: bucket edges by dst>>8, packed (src<<8 | dst&255) ----------------
__global__ void k_bucket(const int* __restrict__ src, const int* __restrict__ dst,
                         int* __restrict__ bucketfill, unsigned int* __restrict__ bucket) {
    __shared__ int lcnt[NB];
    __shared__ int lbase[NB];
    __shared__ int lfill[NB];
    int t = threadIdx.x;
    int e0 = blockIdx.x * EPB;
    int e1 = min(e0 + EPB, NE);
    for (int i = t; i < NB; i += 256) lcnt[i] = 0;
    __syncthreads();
    for (int e = e0 + t; e < e1; e += 256) atomicAdd(&lcnt[dst[e] >> 8], 1);
    __syncthreads();
    for (int i = t; i < NB; i += 256) {
        lbase[i] = (lcnt[i] > 0) ? atomicAdd(&bucketfill[i], lcnt[i]) : 0;
        lfill[i] = 0;
    }
    __syncthreads();
    for (int e = e0 + t; e < e1; e += 256) {
        int d = dst[e], s = src[e];
        int b = d >> 8;
        int p = atomicAdd(&lfill[b], 1);
        bucket[(size_t)b * CAP + lbase[b] + p] = (unsigned)(d & (NPB - 1)) | ((unsigned)s << 8);
    }
}

// ---------------- scan bucket counts -> bucket bases (1 block) ----------------
__global__ void k_scan_nb(const int* __restrict__ bucketfill, int* __restrict__ bucketbase) {
    __shared__ int sdat[512];
    int t = threadIdx.x;
    int v = (t < NB) ? bucketfill[t] : 0;
    sdat[t] = v;
    __syncthreads();
    for (int off = 1; off < 512; off <<= 1) {
        int tv = (t >= off) ? sdat[t - off] : 0;
        __syncthreads();
        sdat[t] += tv;
        __syncthreads();
    }
    if (t < NB) bucketbase[t] = sdat[t] - v;   // exclusive
}

// ---------------- pass 2: per-bucket LDS counting sort -> deg, rowstart, srcs ----------------
__global__ void k_sort(const int* __restrict__ bucketfill, const int* __restrict__ bucketbase,
                       const unsigned int* __restrict__ bucket,
                       int* __restrict__ deg, int* __restrict__ rowstart,
                       int* __restrict__ srcs) {
    __shared__ int lcnt[NPB];
    __shared__ int lscan[NPB];
    __shared__ int lfill[NPB];
    int b = blockIdx.x;
    int t = threadIdx.x;
    int cntb = bucketfill[b];
    int base = bucketbase[b];
    const unsigned int* bk = bucket + (size_t)b * CAP;
    lcnt[t] = 0;
    __syncthreads();
    for (int i = t; i < cntb; i += NPB) atomicAdd(&lcnt[bk[i] & (NPB - 1)], 1);
    __syncthreads();
    lscan[t] = lcnt[t];
    __syncthreads();
    for (int off = 1; off < NPB; off <<= 1) {
        int tv = (t >= off) ? lscan[t - off] : 0;
        __syncthreads();
        lscan[t] += tv;
        __syncthreads();
    }
    int excl = lscan[t] - lcnt[t];
    int node = b * NPB + t;
    if (node < NN) { deg[node] = lcnt[t]; rowstart[node] = base + excl; }
    lfill[t] = excl;
    __syncthreads();
    for (int i = t; i < cntb; i += NPB) {
        unsigned v = bk[i];
        int d = v & (NPB - 1);
        int p = atomicAdd(&lfill[d], 1);
        srcs[base + p] = (int)(v >> 8);
    }
}

// ---------------- pre-transform: z = Wl1*x, rb = Wr1*x + bl1; also u,v,c0 ----------------
__global__ void k_pre1(const float* __restrict__ x,
                       const float* __restrict__ Wl1, const float* __restrict__ bl1,
                       const float* __restrict__ Wr1,
                       const float* __restrict__ Wl2, const float* __restrict__ bl2,
                       const float* __restrict__ Wr2,
                       const float* __restrict__ Wfc, const float* __restrict__ bfc,
                       float* __restrict__ z, float* __restrict__ rb,
                       float* __restrict__ uvc) {
    __shared__ float sWl[HID_DIM * IN_DIM];
    __shared__ float sWr[HID_DIM * IN_DIM];
    __shared__ float sb[HID_DIM];
    for (int i = threadIdx.x; i < HID_DIM * IN_DIM; i += blockDim.x) {
        sWl[i] = Wl1[i];
        sWr[i] = Wr1[i];
    }
    if (threadIdx.x < HID_DIM) sb[threadIdx.x] = bl1[threadIdx.x];
    // block 0 additionally computes u = Wfc*Wl2, v = Wfc*Wr2, c0 = Wfc*bl2 + bfc
    if (blockIdx.x == 0 && threadIdx.x < HID_DIM) {
        int j = threadIdx.x;
        float uu = 0.f, vv = 0.f;
#pragma unroll
        for (int o = 0; o < OUT_DIM; o++) {
            uu += Wfc[o] * Wl2[o * HID_DIM + j];
            vv += Wfc[o] * Wr2[o * HID_DIM + j];
        }
        uvc[j] = uu;
        uvc[HID_DIM + j] = vv;
        if (j == 0) {
            float c0 = bfc[0];
#pragma unroll
            for (int o = 0; o < OUT_DIM; o++) c0 += Wfc[o] * bl2[o];
            uvc[2 * HID_DIM] = c0;
        }
    }
    __syncthreads();

    int n = blockIdx.x * blockDim.x + threadIdx.x;
    if (n >= NN) return;

    float xv[IN_DIM];
    const float4* x4 = (const float4*)(x + (size_t)n * IN_DIM);
#pragma unroll
    for (int c = 0; c < 8; c++) {
        float4 b = x4[c];
        xv[c * 4 + 0] = b.x; xv[c * 4 + 1] = b.y; xv[c * 4 + 2] = b.z; xv[c * 4 + 3] = b.w;
    }
    float zo[HID_DIM], ro[HID_DIM];
#pragma unroll
    for (int o = 0; o < HID_DIM; o++) {
        float az = 0.f, ar = sb[o];
#pragma unroll
        for (int i = 0; i < IN_DIM; i++) {
            az += sWl[o * IN_DIM + i] * xv[i];
            ar += sWr[o * IN_DIM + i] * xv[i];
        }
        zo[o] = az; ro[o] = ar;
    }
    float4* z4 = (float4*)(z + (size_t)n * HID_DIM);
    float4* r4 = (float4*)(rb + (size_t)n * HID_DIM);
#pragma unroll
    for (int c = 0; c < 4; c++) {
        z4[c] = make_float4(zo[c * 4], zo[c * 4 + 1], zo[c * 4 + 2], zo[c * 4 + 3]);
        r4[c] = make_float4(ro[c * 4], ro[c * 4 + 1], ro[c * 4 + 2], ro[c * 4 + 3]);
    }
}

// ---------------- fused gather-mean(z) + layer1 elementwise + dots -> s,t ----------------
// 4 lanes per node, float4 each.
__global__ void k_gather_h(const int* __restrict__ srcs, const int* __restrict__ deg,
                           const int* __restrict__ rowstart,
                           const float* __restrict__ z, const float* __restrict__ rb,
                           const float* __restrict__ uvc,
                           float* __restrict__ s, float* __restrict__ t) {
    int tid = blockIdx.x * blockDim.x + threadIdx.x;
    int n = tid >> 2;
    int c = tid & 3;
    if (n >= NN) return;
    int dg = deg[n];
    int st = rowstart[n];
    float4 acc = {0.f, 0.f, 0.f, 0.f};
    for (int i = 0; i < dg; i++) {
        int sc = srcs[st + i];
        float4 v = ((const float4*)z)[sc * 4 + c];
        acc.x += v.x; acc.y += v.y; acc.z += v.z; acc.w += v.w;
    }
    float inv = 1.0f / fmaxf((float)dg, 1.0f);
    float4 r = ((const float4*)rb)[n * 4 + c];
    float h0 = fmaxf(acc.x * inv + r.x, 0.f);
    float h1 = fmaxf(acc.y * inv + r.y, 0.f);
    float h2 = fmaxf(acc.z * inv + r.z, 0.f);
    float h3 = fmaxf(acc.w * inv + r.w, 0.f);
    float4 u4 = ((const float4*)uvc)[c];
    float4 v4 = ((const float4*)uvc)[4 + c];
    float ps = u4.x * h0 + u4.y * h1 + u4.z * h2 + u4.w * h3;
    float pt = v4.x * h0 + v4.y * h1 + v4.z * h2 + v4.w * h3;
    ps += __shfl_xor(ps, 1);
    ps += __shfl_xor(ps, 2);
    pt += __shfl_xor(pt, 1);
    pt += __shfl_xor(pt, 2);
    if (c == 0) { s[n] = ps; t[n] = pt; }
}

// ---------------- final: out = mean(s[src]) + t + c0 ----------------
__global__ void k_final(const int* __restrict__ srcs, const int* __restrict__ deg,
                        const int* __restrict__ rowstart,
                        const float* __restrict__ s, const float* __restrict__ t,
                        const float* __restrict__ uvc, float* __restrict__ out) {
    int n = blockIdx.x * blockDim.x + threadIdx.x;
    if (n >= NN) return;
    int dg = deg[n];
    int st = rowstart[n];
    float acc = 0.f;
    for (int i = 0; i < dg; i++) acc += s[srcs[st + i]];
    out[n] = acc / fmaxf((float)dg, 1.0f) + t[n] + uvc[2 * HID_DIM];
}

extern "C" void kernel_launch(void* const* d_in, const int* in_sizes, int n_in,
                              void* d_out, int out_size, void* d_ws, size_t ws_size,
                              hipStream_t stream) {
    const float* x   = (const float*)d_in[0];
    const int*   ei  = (const int*)d_in[1];
    const float* Wl1 = (const float*)d_in[2];
    const float* bl1 = (const float*)d_in[3];
    const float* Wr1 = (const float*)d_in[4];
    const float* Wl2 = (const float*)d_in[5];
    const float* bl2 = (const float*)d_in[6];
    const float* Wr2 = (const float*)d_in[7];
    const float* Wfc = (const float*)d_in[8];
    const float* bfc = (const float*)d_in[9];
    float* out = (float*)d_out;

    const int* src = ei;
    const int* dst = ei + NE;

    // ws layout (all offsets kept 16B-aligned):
    // bucketfill[400] | bucketbase[400] | deg[100000] | rowstart[100000] | srcs[1600000] |
    // uvc[40] | s[100000] | t[100000] | bucket[NB*CAP] | z[NN*16] | rb[NN*16]
    int* bucketfill = (int*)d_ws;
    int* bucketbase = bucketfill + 400;
    int* deg        = bucketbase + 400;
    int* rowstart   = deg + NN;
    int* srcs       = rowstart + NN;
    float* uvc      = (float*)(srcs + NE);
    float* s        = uvc + 40;
    float* t        = s + NN;
    unsigned int* bucket = (unsigned int*)(t + NN);
    float* z        = (float*)(bucket + (size_t)NB * CAP);
    float* rb       = z + (size_t)NN * HID_DIM;

    hipMemsetAsync(bucketfill, 0, NB * sizeof(int), stream);

    k_bucket<<<NBLK_BUCKET, 256, 0, stream>>>(src, dst, bucketfill, bucket);
    k_scan_nb<<<1, 512, 0, stream>>>(bucketfill, bucketbase);
    k_sort<<<NB, NPB, 0, stream>>>(bucketfill, bucketbase, bucket, deg, rowstart, srcs);

    k_pre1<<<(NN + 255) / 256, 256, 0, stream>>>(x, Wl1, bl1, Wr1, Wl2, bl2, Wr2, Wfc, bfc,
                                                 z, rb, uvc);
    k_gather_h<<<((size_t)NN * 4 + 255) / 256, 256, 0, stream>>>(srcs, deg, rowstart,
                                                                 z, rb, uvc, s, t);
    k_final<<<(NN + 255) / 256, 256, 0, stream>>>(srcs, deg, rowstart, s, t, uvc, out);
}

// Round 6
// 177.537 us; speedup vs baseline: 6.4656x; 1.0628x over previous
//
#include <hip/hip_runtime.h>

#define NN 100000
#define NE 1600000
#define IN_DIM 32
#define HID_DIM 16
#define OUT_DIM 8

#define NPB 256                       // nodes per bucket
#define NBK ((NN + NPB - 1) / NPB)    // 391 buckets
#define CAP 5632                      // bucket capacity (mean 4092, ~24 sigma)
#define EPB 2048                      // edges per bucket-task
#define NT_BUCKET ((NE + EPB - 1) / EPB)   // 782
#define NT_PRE1 ((NN + 255) / 256)         // 391
#define GRID1 (NT_BUCKET + NT_PRE1)        // 1173

// =============== kernel 1: bucket edges (blocks 0..781)  ||  pre1 (blocks 782..1172) ===============
__global__ __launch_bounds__(256) void k_phase1(
    const float* __restrict__ x, const int* __restrict__ src, const int* __restrict__ dst,
    const float* __restrict__ Wl1, const float* __restrict__ bl1, const float* __restrict__ Wr1,
    const float* __restrict__ Wl2, const float* __restrict__ bl2, const float* __restrict__ Wr2,
    const float* __restrict__ Wfc, const float* __restrict__ bfc,
    int* __restrict__ bucketfill, unsigned int* __restrict__ bucket,
    float* __restrict__ z, float* __restrict__ rb, float* __restrict__ uvc)
{
    __shared__ char smemraw[4800];
    int tid = threadIdx.x;

    if (blockIdx.x < NT_BUCKET) {
        int* lcnt  = (int*)smemraw;
        int* lbase = lcnt + NBK;
        int* lfill = lbase + NBK;
        int e0 = blockIdx.x * EPB;
        int e1 = min(e0 + EPB, NE);
        for (int i = tid; i < NBK; i += 256) lcnt[i] = 0;
        __syncthreads();
        for (int e = e0 + tid; e < e1; e += 256) atomicAdd(&lcnt[dst[e] >> 8], 1);
        __syncthreads();
        for (int i = tid; i < NBK; i += 256) {
            lbase[i] = (lcnt[i] > 0) ? atomicAdd(&bucketfill[i], lcnt[i]) : 0;
            lfill[i] = 0;
        }
        __syncthreads();
        for (int e = e0 + tid; e < e1; e += 256) {
            int d = dst[e], s = src[e];
            int b = d >> 8;
            int p = atomicAdd(&lfill[b], 1);
            bucket[(size_t)b * CAP + lbase[b] + p] =
                (unsigned)(d & (NPB - 1)) | ((unsigned)s << 8);
        }
    } else {
        int chunk = blockIdx.x - NT_BUCKET;
        float* sWl = (float*)smemraw;        // 512
        float* sWr = sWl + 512;              // 512
        float* sb  = sWr + 512;              // 16
        for (int i = tid; i < HID_DIM * IN_DIM; i += 256) {
            sWl[i] = Wl1[i];
            sWr[i] = Wr1[i];
        }
        if (tid < HID_DIM) sb[tid] = bl1[tid];
        if (chunk == 0) {
            if (tid < HID_DIM) {
                float uu = 0.f, vv = 0.f;
#pragma unroll
                for (int o = 0; o < OUT_DIM; o++) {
                    uu += Wfc[o] * Wl2[o * HID_DIM + tid];
                    vv += Wfc[o] * Wr2[o * HID_DIM + tid];
                }
                uvc[tid] = uu;
                uvc[HID_DIM + tid] = vv;
            }
            if (tid == 0) {
                float c0 = bfc[0];
#pragma unroll
                for (int o = 0; o < OUT_DIM; o++) c0 += Wfc[o] * bl2[o];
                uvc[2 * HID_DIM] = c0;
            }
        }
        __syncthreads();
        int n = chunk * 256 + tid;
        if (n < NN) {
            float xv[IN_DIM];
            const float4* x4 = (const float4*)(x + (size_t)n * IN_DIM);
#pragma unroll
            for (int c = 0; c < 8; c++) {
                float4 b = x4[c];
                xv[c * 4 + 0] = b.x; xv[c * 4 + 1] = b.y;
                xv[c * 4 + 2] = b.z; xv[c * 4 + 3] = b.w;
            }
            float zo[HID_DIM], ro[HID_DIM];
#pragma unroll
            for (int o = 0; o < HID_DIM; o++) {
                float az = 0.f, ar = sb[o];
#pragma unroll
                for (int i = 0; i < IN_DIM; i++) {
                    az += sWl[o * IN_DIM + i] * xv[i];
                    ar += sWr[o * IN_DIM + i] * xv[i];
                }
                zo[o] = az; ro[o] = ar;
            }
            float4* z4 = (float4*)(z + (size_t)n * HID_DIM);
            float4* r4 = (float4*)(rb + (size_t)n * HID_DIM);
#pragma unroll
            for (int c = 0; c < 4; c++) {
                z4[c] = make_float4(zo[c*4], zo[c*4+1], zo[c*4+2], zo[c*4+3]);
                r4[c] = make_float4(ro[c*4], ro[c*4+1], ro[c*4+2], ro[c*4+3]);
            }
        }
    }
}

// =============== kernel 2: per-bucket sort (LDS) + fused gather_h for own nodes ===============
__global__ __launch_bounds__(256) void k_sort_gather(
    const int* __restrict__ bucketfill, const unsigned int* __restrict__ bucket,
    const float* __restrict__ z, const float* __restrict__ rb, const float* __restrict__ uvc,
    int* __restrict__ deg, int* __restrict__ rowstart, int* __restrict__ srcs,
    float* __restrict__ sv, float* __restrict__ tv)
{
    __shared__ int lcnt[NPB];
    __shared__ int lscan[NPB];
    __shared__ int lfill[NPB];
    __shared__ int lred[NPB];
    __shared__ int ssrc[CAP];

    int b = blockIdx.x;
    int tid = threadIdx.x;

    // base = prefix sum of bucketfill[0..b)
    int part = 0;
    for (int i = tid; i < b; i += 256) part += bucketfill[i];
    lred[tid] = part;
    __syncthreads();
    for (int off = 128; off > 0; off >>= 1) {
        if (tid < off) lred[tid] += lred[tid + off];
        __syncthreads();
    }
    int base = lred[0];
    int cntb = bucketfill[b];
    const unsigned int* bk = bucket + (size_t)b * CAP;

    lcnt[tid] = 0;
    __syncthreads();
    for (int i = tid; i < cntb; i += 256) atomicAdd(&lcnt[bk[i] & (NPB - 1)], 1);
    __syncthreads();
    lscan[tid] = lcnt[tid];
    __syncthreads();
    for (int off = 1; off < 256; off <<= 1) {
        int tvv = (tid >= off) ? lscan[tid - off] : 0;
        __syncthreads();
        lscan[tid] += tvv;
        __syncthreads();
    }
    int excl = lscan[tid] - lcnt[tid];
    lfill[tid] = excl;
    int node = b * NPB + tid;
    if (node < NN) { deg[node] = lcnt[tid]; rowstart[node] = base + excl; }
    __syncthreads();
    for (int i = tid; i < cntb; i += 256) {
        unsigned v = bk[i];
        int d = v & (NPB - 1);
        int p = atomicAdd(&lfill[d], 1);
        int s = (int)(v >> 8);
        ssrc[p] = s;
        srcs[base + p] = s;
    }
    __syncthreads();

    // fused gather_h: 4 passes x (64 nodes x 4 lanes)
    int c = tid & 3;
    int nl0 = tid >> 2;
    float4 u4 = ((const float4*)uvc)[c];
    float4 v4 = ((const float4*)uvc)[4 + c];
#pragma unroll
    for (int pass = 0; pass < 4; pass++) {
        int nl = pass * 64 + nl0;
        int n2 = b * NPB + nl;
        if (n2 < NN) {
            int dg = lcnt[nl];
            int st = lscan[nl] - dg;
            float4 acc = {0.f, 0.f, 0.f, 0.f};
            for (int i = 0; i < dg; i++) {
                int sc = ssrc[st + i];
                float4 vz = ((const float4*)z)[sc * 4 + c];
                acc.x += vz.x; acc.y += vz.y; acc.z += vz.z; acc.w += vz.w;
            }
            float inv = 1.0f / fmaxf((float)dg, 1.0f);
            float4 r = ((const float4*)rb)[n2 * 4 + c];
            float h0 = fmaxf(acc.x * inv + r.x, 0.f);
            float h1 = fmaxf(acc.y * inv + r.y, 0.f);
            float h2 = fmaxf(acc.z * inv + r.z, 0.f);
            float h3 = fmaxf(acc.w * inv + r.w, 0.f);
            float ps = u4.x * h0 + u4.y * h1 + u4.z * h2 + u4.w * h3;
            float pt = v4.x * h0 + v4.y * h1 + v4.z * h2 + v4.w * h3;
            ps += __shfl_xor(ps, 1);
            ps += __shfl_xor(ps, 2);
            pt += __shfl_xor(pt, 1);
            pt += __shfl_xor(pt, 2);
            if (c == 0) { sv[n2] = ps; tv[n2] = pt; }
        }
    }
}

// =============== kernel 3: out = mean(sv[src]) + tv + c0 (4 lanes/node) ===============
__global__ __launch_bounds__(256) void k_final(
    const int* __restrict__ srcs, const int* __restrict__ deg, const int* __restrict__ rowstart,
    const float* __restrict__ sv, const float* __restrict__ tv,
    const float* __restrict__ uvc, float* __restrict__ out)
{
    int v = blockIdx.x * 256 + threadIdx.x;
    if (v >= NN * 4) return;
    int n = v >> 2;
    int c = v & 3;
    int dg = deg[n];
    int st = rowstart[n];
    float acc = 0.f;
    for (int i = c; i < dg; i += 4) acc += sv[srcs[st + i]];
    acc += __shfl_xor(acc, 1);
    acc += __shfl_xor(acc, 2);
    if (c == 0) out[n] = acc / fmaxf((float)dg, 1.0f) + tv[n] + uvc[2 * HID_DIM];
}

extern "C" void kernel_launch(void* const* d_in, const int* in_sizes, int n_in,
                              void* d_out, int out_size, void* d_ws, size_t ws_size,
                              hipStream_t stream) {
    const float* x   = (const float*)d_in[0];
    const int*   ei  = (const int*)d_in[1];
    const float* Wl1 = (const float*)d_in[2];
    const float* bl1 = (const float*)d_in[3];
    const float* Wr1 = (const float*)d_in[4];
    const float* Wl2 = (const float*)d_in[5];
    const float* bl2 = (const float*)d_in[6];
    const float* Wr2 = (const float*)d_in[7];
    const float* Wfc = (const float*)d_in[8];
    const float* bfc = (const float*)d_in[9];
    float* out = (float*)d_out;

    const int* src = ei;
    const int* dst = ei + NE;

    // ws layout:
    int* bucketfill = (int*)d_ws;                        // 400
    int* deg        = bucketfill + 400;                  // NN
    int* rowstart   = deg + NN;                          // NN
    int* srcs       = rowstart + NN;                     // NE
    float* uvc      = (float*)(srcs + NE);               // 40
    float* sv       = uvc + 40;                          // NN
    float* tv       = sv + NN;                           // NN
    unsigned int* bucket = (unsigned int*)(tv + NN);     // NBK*CAP
    float* z        = (float*)(bucket + (size_t)NBK * CAP);  // NN*16
    float* rb       = z + (size_t)NN * HID_DIM;              // NN*16

    hipMemsetAsync(bucketfill, 0, NBK * sizeof(int), stream);

    k_phase1<<<GRID1, 256, 0, stream>>>(x, src, dst, Wl1, bl1, Wr1,
                                        Wl2, bl2, Wr2, Wfc, bfc,
                                        bucketfill, bucket, z, rb, uvc);
    k_sort_gather<<<NBK, 256, 0, stream>>>(bucketfill, bucket, z, rb, uvc,
                                           deg, rowstart, srcs, sv, tv);
    k_final<<<((NN * 4) + 255) / 256, 256, 0, stream>>>(srcs, deg, rowstart, sv, tv, uvc, out);
}

// Round 8
// 164.036 us; speedup vs baseline: 6.9977x; 1.0823x over previous
//
#include <hip/hip_runtime.h>

#define NN 100000
#define NE 1600000
#define IN_DIM 32
#define HID_DIM 16
#define OUT_DIM 8

#define NPB 256                       // nodes per bucket
#define NBK ((NN + NPB - 1) / NPB)    // 391 buckets
#define CAP 5632                      // bucket capacity (mean 4092, ~24 sigma)
#define EPB 4096                      // edges per bucket-task (proven in R2/R3)
#define NT_BUCKET ((NE + EPB - 1) / EPB)   // 391
#define NT_PRE1 ((NN + 255) / 256)         // 391
#define GRID1 (NT_BUCKET + NT_PRE1)        // 782
#define BF_STRIDE 16                  // bucketfill padding: 1 counter per 64B line

// =============== kernel 1: bucket edges (blocks 0..390)  ||  pre1 (blocks 391..781) ===============
__global__ __launch_bounds__(256) void k_phase1(
    const float* __restrict__ x, const int* __restrict__ src, const int* __restrict__ dst,
    const float* __restrict__ Wl1, const float* __restrict__ bl1, const float* __restrict__ Wr1,
    const float* __restrict__ Wl2, const float* __restrict__ bl2, const float* __restrict__ Wr2,
    const float* __restrict__ Wfc, const float* __restrict__ bfc,
    int* __restrict__ bucketfill, unsigned int* __restrict__ bucket,
    float* __restrict__ z, float* __restrict__ rb, float* __restrict__ uvc)
{
    __shared__ char smemraw[4800];
    int tid = threadIdx.x;

    if (blockIdx.x < NT_BUCKET) {
        int* lcnt  = (int*)smemraw;
        int* lbase = lcnt + NBK;
        int* lfill = lbase + NBK;
        int e0 = blockIdx.x * EPB;
        int e1 = min(e0 + EPB, NE);
        for (int i = tid; i < NBK; i += 256) lcnt[i] = 0;
        __syncthreads();
        for (int e = e0 + tid; e < e1; e += 256) atomicAdd(&lcnt[dst[e] >> 8], 1);
        __syncthreads();
        for (int i = tid; i < NBK; i += 256) {
            lbase[i] = (lcnt[i] > 0) ? atomicAdd(&bucketfill[i * BF_STRIDE], lcnt[i]) : 0;
            lfill[i] = 0;
        }
        __syncthreads();
        for (int e = e0 + tid; e < e1; e += 256) {
            int d = dst[e], s = src[e];
            int b = d >> 8;
            int p = atomicAdd(&lfill[b], 1);
            bucket[(size_t)b * CAP + lbase[b] + p] =
                (unsigned)(d & (NPB - 1)) | ((unsigned)s << 8);
        }
    } else {
        int chunk = blockIdx.x - NT_BUCKET;
        float* sWl = (float*)smemraw;        // 512
        float* sWr = sWl + 512;              // 512
        float* sb  = sWr + 512;              // 16
        for (int i = tid; i < HID_DIM * IN_DIM; i += 256) {
            sWl[i] = Wl1[i];
            sWr[i] = Wr1[i];
        }
        if (tid < HID_DIM) sb[tid] = bl1[tid];
        if (chunk == 0) {
            if (tid < HID_DIM) {
                float uu = 0.f, vv = 0.f;
#pragma unroll
                for (int o = 0; o < OUT_DIM; o++) {
                    uu += Wfc[o] * Wl2[o * HID_DIM + tid];
                    vv += Wfc[o] * Wr2[o * HID_DIM + tid];
                }
                uvc[tid] = uu;
                uvc[HID_DIM + tid] = vv;
            }
            if (tid == 0) {
                float c0 = bfc[0];
#pragma unroll
                for (int o = 0; o < OUT_DIM; o++) c0 += Wfc[o] * bl2[o];
                uvc[2 * HID_DIM] = c0;
            }
        }
        __syncthreads();
        int n = chunk * 256 + tid;
        if (n < NN) {
            float xv[IN_DIM];
            const float4* x4 = (const float4*)(x + (size_t)n * IN_DIM);
#pragma unroll
            for (int c = 0; c < 8; c++) {
                float4 b = x4[c];
                xv[c * 4 + 0] = b.x; xv[c * 4 + 1] = b.y;
                xv[c * 4 + 2] = b.z; xv[c * 4 + 3] = b.w;
            }
            float zo[HID_DIM], ro[HID_DIM];
#pragma unroll
            for (int o = 0; o < HID_DIM; o++) {
                float az = 0.f, ar = sb[o];
#pragma unroll
                for (int i = 0; i < IN_DIM; i++) {
                    az += sWl[o * IN_DIM + i] * xv[i];
                    ar += sWr[o * IN_DIM + i] * xv[i];
                }
                zo[o] = az; ro[o] = ar;
            }
            float4* z4 = (float4*)(z + (size_t)n * HID_DIM);
            float4* r4 = (float4*)(rb + (size_t)n * HID_DIM);
#pragma unroll
            for (int c = 0; c < 4; c++) {
                z4[c] = make_float4(zo[c*4], zo[c*4+1], zo[c*4+2], zo[c*4+3]);
                r4[c] = make_float4(ro[c*4], ro[c*4+1], ro[c*4+2], ro[c*4+3]);
            }
        }
    }
}

// =============== kernel 2: per-bucket sort (LDS) + fused gather_h for own nodes ===============
__global__ __launch_bounds__(256) void k_sort_gather(
    const int* __restrict__ bucketfill, const unsigned int* __restrict__ bucket,
    const float* __restrict__ z, const float* __restrict__ rb, const float* __restrict__ uvc,
    int* __restrict__ deg, int* __restrict__ rowstart, int* __restrict__ srcs,
    float* __restrict__ sv, float* __restrict__ tv)
{
    __shared__ int lcnt[NPB];
    __shared__ int lscan[NPB];
    __shared__ int lfill[NPB];
    __shared__ int lred[NPB];
    __shared__ int ssrc[CAP];

    int b = blockIdx.x;
    int tid = threadIdx.x;

    // base = prefix sum of bucketfill[0..b)
    int part = 0;
    for (int i = tid; i < b; i += 256) part += bucketfill[i * BF_STRIDE];
    lred[tid] = part;
    __syncthreads();
    for (int off = 128; off > 0; off >>= 1) {
        if (tid < off) lred[tid] += lred[tid + off];
        __syncthreads();
    }
    int base = lred[0];
    int cntb = bucketfill[b * BF_STRIDE];
    const unsigned int* bk = bucket + (size_t)b * CAP;

    lcnt[tid] = 0;
    __syncthreads();
    for (int i = tid; i < cntb; i += 256) atomicAdd(&lcnt[bk[i] & (NPB - 1)], 1);
    __syncthreads();
    lscan[tid] = lcnt[tid];
    __syncthreads();
    for (int off = 1; off < 256; off <<= 1) {
        int tvv = (tid >= off) ? lscan[tid - off] : 0;
        __syncthreads();
        lscan[tid] += tvv;
        __syncthreads();
    }
    int excl = lscan[tid] - lcnt[tid];
    lfill[tid] = excl;
    int node = b * NPB + tid;
    if (node < NN) { deg[node] = lcnt[tid]; rowstart[node] = base + excl; }
    __syncthreads();
    for (int i = tid; i < cntb; i += 256) {
        unsigned v = bk[i];
        int d = v & (NPB - 1);
        int p = atomicAdd(&lfill[d], 1);
        int s = (int)(v >> 8);
        ssrc[p] = s;
        srcs[base + p] = s;
    }
    __syncthreads();

    // fused gather_h: 4 passes x (64 nodes x 4 lanes)
    int c = tid & 3;
    int nl0 = tid >> 2;
    float4 u4 = ((const float4*)uvc)[c];
    float4 v4 = ((const float4*)uvc)[4 + c];
#pragma unroll
    for (int pass = 0; pass < 4; pass++) {
        int nl = pass * 64 + nl0;
        int n2 = b * NPB + nl;
        if (n2 < NN) {
            int dg = lcnt[nl];
            int st = lscan[nl] - dg;
            float4 acc = {0.f, 0.f, 0.f, 0.f};
            for (int i = 0; i < dg; i++) {
                int sc = ssrc[st + i];
                float4 vz = ((const float4*)z)[sc * 4 + c];
                acc.x += vz.x; acc.y += vz.y; acc.z += vz.z; acc.w += vz.w;
            }
            float inv = 1.0f / fmaxf((float)dg, 1.0f);
            float4 r = ((const float4*)rb)[n2 * 4 + c];
            float h0 = fmaxf(acc.x * inv + r.x, 0.f);
            float h1 = fmaxf(acc.y * inv + r.y, 0.f);
            float h2 = fmaxf(acc.z * inv + r.z, 0.f);
            float h3 = fmaxf(acc.w * inv + r.w, 0.f);
            float ps = u4.x * h0 + u4.y * h1 + u4.z * h2 + u4.w * h3;
            float pt = v4.x * h0 + v4.y * h1 + v4.z * h2 + v4.w * h3;
            ps += __shfl_xor(ps, 1);
            ps += __shfl_xor(ps, 2);
            pt += __shfl_xor(pt, 1);
            pt += __shfl_xor(pt, 2);
            if (c == 0) { sv[n2] = ps; tv[n2] = pt; }
        }
    }
}

// =============== kernel 3: out = mean(sv[src]) + tv + c0 (4 lanes/node) ===============
__global__ __launch_bounds__(256) void k_final(
    const int* __restrict__ srcs, const int* __restrict__ deg, const int* __restrict__ rowstart,
    const float* __restrict__ sv, const float* __restrict__ tv,
    const float* __restrict__ uvc, float* __restrict__ out)
{
    int v = blockIdx.x * 256 + threadIdx.x;
    if (v >= NN * 4) return;
    int n = v >> 2;
    int c = v & 3;
    int dg = deg[n];
    int st = rowstart[n];
    float acc = 0.f;
    for (int i = c; i < dg; i += 4) acc += sv[srcs[st + i]];
    acc += __shfl_xor(acc, 1);
    acc += __shfl_xor(acc, 2);
    if (c == 0) out[n] = acc / fmaxf((float)dg, 1.0f) + tv[n] + uvc[2 * HID_DIM];
}

extern "C" void kernel_launch(void* const* d_in, const int* in_sizes, int n_in,
                              void* d_out, int out_size, void* d_ws, size_t ws_size,
                              hipStream_t stream) {
    const float* x   = (const float*)d_in[0];
    const int*   ei  = (const int*)d_in[1];
    const float* Wl1 = (const float*)d_in[2];
    const float* bl1 = (const float*)d_in[3];
    const float* Wr1 = (const float*)d_in[4];
    const float* Wl2 = (const float*)d_in[5];
    const float* bl2 = (const float*)d_in[6];
    const float* Wr2 = (const float*)d_in[7];
    const float* Wfc = (const float*)d_in[8];
    const float* bfc = (const float*)d_in[9];
    float* out = (float*)d_out;

    const int* src = ei;
    const int* dst = ei + NE;

    // ws layout:
    int* bucketfill = (int*)d_ws;                        // NBK*BF_STRIDE = 6256 (pad to 6400)
    int* deg        = bucketfill + 6400;                 // NN
    int* rowstart   = deg + NN;                          // NN
    int* srcs       = rowstart + NN;                     // NE
    float* uvc      = (float*)(srcs + NE);               // 40
    float* sv       = uvc + 40;                          // NN
    float* tv       = sv + NN;                           // NN
    unsigned int* bucket = (unsigned int*)(tv + NN);     // NBK*CAP
    float* z        = (float*)(bucket + (size_t)NBK * CAP);  // NN*16
    float* rb       = z + (size_t)NN * HID_DIM;              // NN*16

    hipMemsetAsync(bucketfill, 0, NBK * BF_STRIDE * sizeof(int), stream);

    k_phase1<<<GRID1, 256, 0, stream>>>(x, src, dst, Wl1, bl1, Wr1,
                                        Wl2, bl2, Wr2, Wfc, bfc,
                                        bucketfill, bucket, z, rb, uvc);
    k_sort_gather<<<NBK, 256, 0, stream>>>(bucketfill, bucket, z, rb, uvc,
                                           deg, rowstart, srcs, sv, tv);
    k_final<<<((NN * 4) + 255) / 256, 256, 0, stream>>>(srcs, deg, rowstart, sv, tv, uvc, out);
}